// Round 13
// baseline (285.334 us; speedup 1.0000x reference)
//
#include <hip/hip_runtime.h>

using f32x4  = __attribute__((ext_vector_type(4))) float;
using bf16x8 = __attribute__((ext_vector_type(8))) __bf16;
using f16x8  = __attribute__((ext_vector_type(8))) _Float16;
using u16x4  = __attribute__((ext_vector_type(4))) unsigned short;
using u16x8  = __attribute__((ext_vector_type(8))) unsigned short;

constexpr int Bb = 4, SQn = 2048, SKn = 2048, Dd = 1024;

__device__ __forceinline__ unsigned fbitsu(float x){ union{float f;unsigned u;}c; c.f=x; return c.u; }
__device__ __forceinline__ float ubitsf(unsigned u){ union{unsigned u;float f;}c; c.u=u; return c.f; }
__device__ __forceinline__ unsigned short hi_trunc(float x){ return (unsigned short)(fbitsu(x)>>16); }
__device__ __forceinline__ unsigned short hi_rne(float x){ unsigned u=fbitsu(x); return (unsigned short)((u + 0x7FFFu + ((u>>16)&1u))>>16); }
__device__ __forceinline__ float from_hi(unsigned short h){ return ubitsf(((unsigned)h)<<16); }
__device__ __forceinline__ unsigned short h_rne(float x){ _Float16 h = (_Float16)x; return __builtin_bit_cast(unsigned short, h); }
__device__ __forceinline__ float h2f(unsigned short u){ return (float)__builtin_bit_cast(_Float16, u); }

template<int DT> __device__ __forceinline__ unsigned short cvt_rne(float x){ return DT ? h_rne(x) : hi_rne(x); }
template<int DT> __device__ __forceinline__ float cvt_f(unsigned short u){ return DT ? h2f(u) : from_hi(u); }

__device__ __forceinline__ f32x4 mfma_bf16(bf16x8 a, bf16x8 b, f32x4 c){
    return __builtin_amdgcn_mfma_f32_16x16x32_bf16(a, b, c, 0, 0, 0);
}
__device__ __forceinline__ f32x4 mfma_f16(u16x8 a, u16x8 b, f32x4 c){
    return __builtin_amdgcn_mfma_f32_16x16x32_f16(
        __builtin_bit_cast(f16x8, a), __builtin_bit_cast(f16x8, b), c, 0, 0, 0);
}
template<int DT>
__device__ __forceinline__ f32x4 mfma_u16(u16x8 a, u16x8 b, f32x4 c){
    if constexpr (DT) return mfma_f16(a, b, c);
    else return __builtin_amdgcn_mfma_f32_16x16x32_bf16(
        __builtin_bit_cast(bf16x8, a), __builtin_bit_cast(bf16x8, b), c, 0, 0, 0);
}

__device__ __forceinline__ void gload16(const void* g, void* l){
    __builtin_amdgcn_global_load_lds(
        (const __attribute__((address_space(1))) unsigned int*)g,
        (__attribute__((address_space(3))) unsigned int*)l, 16, 0, 0);
}

// Bijective XCD-aware block swizzle (T1). Requires nwg % 8 == 0.
__device__ __forceinline__ void xcd_swz(int& bx, int& by){
    const int nx = gridDim.x, nwg = nx * gridDim.y;
    int l = by * nx + bx;
    l = (l & 7) * (nwg >> 3) + (l >> 3);
    bx = l % nx; by = l / nx;
}

// ---------------------------------------------------------------------------
// Fused prep: x/c fp32 -> fp16 hi/lo splits, plus Wq/Wk/Wv fp32 -> fp16 RNE.
// ---------------------------------------------------------------------------
__global__ __launch_bounds__(256)
void prep(const float* __restrict__ x, const float* __restrict__ c,
          const float* __restrict__ Wq, const float* __restrict__ Wk,
          const float* __restrict__ Wv,
          unsigned short* __restrict__ xh, unsigned short* __restrict__ xl,
          unsigned short* __restrict__ ch, unsigned short* __restrict__ cl,
          unsigned short* __restrict__ oq, unsigned short* __restrict__ ok,
          unsigned short* __restrict__ ov,
          int n4, int nw4)
{
    const int total = 2*n4 + 3*nw4;
    const int stride = gridDim.x * 256;
    for (int i = blockIdx.x * 256 + threadIdx.x; i < total; i += stride) {
        if (i < 2*n4) {
            const bool second = (i >= n4);
            const int j = second ? i - n4 : i;
            const float* in = second ? c : x;
            unsigned short* hi = second ? ch : xh;
            unsigned short* lo = second ? cl : xl;
            float a[4]; *(float4*)a = *(const float4*)(in + (size_t)j * 4);
            u16x4 h, l;
#pragma unroll
            for (int r = 0; r < 4; ++r) {
                h[r] = h_rne(a[r]);
                l[r] = h_rne(a[r] - h2f(h[r]));
            }
            *(u16x4*)&hi[(size_t)j * 4] = h;
            *(u16x4*)&lo[(size_t)j * 4] = l;
        } else {
            int j = i - 2*n4;
            const float* src; unsigned short* dst;
            if (j < nw4)          { src = Wq; dst = oq; }
            else if (j < 2*nw4)   { src = Wk; dst = ok; j -= nw4; }
            else                  { src = Wv; dst = ov; j -= 2*nw4; }
            float a[4]; *(float4*)a = *(const float4*)(src + (size_t)j * 4);
            u16x4 h;
#pragma unroll
            for (int r = 0; r < 4; ++r) h[r] = h_rne(a[r]);
            *(u16x4*)&dst[(size_t)j * 4] = h;
        }
    }
}

// ---------------------------------------------------------------------------
// Scores GEMM: S = [Qh|Ql] . [K|K]^T  (K_eff = 2K, single term, fp16 MFMA).
// Counted-vmcnt double buffer (r10 sync structure, proven correct) at only
// 32 KB LDS -> occupancy preserved (~5 blk/CU) unlike r10's 48 KB version.
// Per iteration: stage(t+1) [4 gloads] -> vmcnt(4) -> barrier -> 16 MFMA ->
// barrier. Split-fp16 epilogue. z-batched, XCD-swizzled.
// ---------------------------------------------------------------------------
__global__ __launch_bounds__(256, 2)
void gemm_sc(const unsigned short* __restrict__ Qhg, const unsigned short* __restrict__ Qlg,
             const unsigned short* __restrict__ Khg,
             unsigned short* __restrict__ Shi, unsigned short* __restrict__ Slo,
             int M, int N, int K, long aBS, long bBS, long oBS)
{
    constexpr int BM_ = 128, BN_ = 128;
    __shared__ __align__(16) unsigned short Ash[2][BM_*32], Bsh[2][BN_*32];

    const int z = blockIdx.z;
    Qhg += (size_t)z * aBS;
    Qlg += (size_t)z * aBS;
    Khg += (size_t)z * bBS;

    int bx = blockIdx.x, by = blockIdx.y;
    xcd_swz(bx, by);

    const int tid = threadIdx.x, lane = tid & 63, w = tid >> 6;
    const int wr = (w >> 1) * 64, wc = (w & 1) * 64;
    const int lr = lane & 15, lg = lane >> 4;
    const int m0 = by * BM_, n0 = bx * BN_;
    const int rowc = lane >> 2;          // 0..15
    const int colb = (lane & 3) << 4;    // 0,16,32,48 bytes
    const size_t rsBy = (size_t)K * 2;

    auto stage = [&](int t, int buf){
        const int k0 = t * 32;
        const bool lo = (k0 >= K);
        const unsigned short* Ap = lo ? Qlg : Qhg;
        const int km = lo ? k0 - K : k0;
#pragma unroll
        for (int c4 = 0; c4 < 2; ++c4) {
            const int c = c4*4 + w;
            const size_t goA = (size_t)(m0 + c*16 + rowc) * rsBy + (size_t)km*2 + colb;
            gload16((const char*)Ap + goA, (char*)&Ash[buf][0] + c*1024);
            const size_t goB = (size_t)(n0 + c*16 + rowc) * rsBy + (size_t)km*2 + colb;
            gload16((const char*)Khg + goB, (char*)&Bsh[buf][0] + c*1024);
        }
    };

    f32x4 acc[4][4] = {};
    const int nt = (2 * K) / 32;         // 64

    stage(0, 0);
    for (int t = 0; t < nt; ++t) {
        const int cur = t & 1;
        if (t + 1 < nt) {
            stage(t + 1, cur ^ 1);
            asm volatile("s_waitcnt vmcnt(4)" ::: "memory");
        } else {
            asm volatile("s_waitcnt vmcnt(0)" ::: "memory");
        }
        __builtin_amdgcn_sched_barrier(0);
        __builtin_amdgcn_s_barrier();

        u16x8 af[4], bf[4];
#pragma unroll
        for (int i = 0; i < 4; ++i) af[i] = *(const u16x8*)&Ash[cur][(wr + i*16 + lr)*32 + lg*8];
#pragma unroll
        for (int j = 0; j < 4; ++j) bf[j] = *(const u16x8*)&Bsh[cur][(wc + j*16 + lr)*32 + lg*8];
#pragma unroll
        for (int i = 0; i < 4; ++i)
#pragma unroll
            for (int j = 0; j < 4; ++j)
                acc[i][j] = mfma_f16(af[i], bf[j], acc[i][j]);

        __builtin_amdgcn_s_barrier();
    }

    unsigned short* Chi = Shi + (size_t)z * oBS;
    unsigned short* Clo = Slo + (size_t)z * oBS;
#pragma unroll
    for (int j = 0; j < 4; ++j) {
        const int col = n0 + wc + j*16 + lr;
#pragma unroll
        for (int i = 0; i < 4; ++i)
#pragma unroll
            for (int r = 0; r < 4; ++r) {
                const size_t idx = (size_t)(m0 + wr + i*16 + lg*4 + r) * N + col;
                const float v = acc[i][j][r];
                const unsigned short h = h_rne(v);
                Chi[idx] = h;
                Clo[idx] = h_rne(v - h2f(h));
            }
    }
}

// ---------------------------------------------------------------------------
// Unified 16-bit NT GEMM, single-buffer (r9-proven sync structure).
// K-step = KS*32, LDS as KS separate 32-col sub-arrays (64B rows always).
// KS=2 wins when B-panel is L2-resident (proj); KS=1 when staging streams.
// ---------------------------------------------------------------------------
template<int TERMS, int BM_, int BN_, int KS, int EPI, int DT>
__global__ __launch_bounds__(256, 2)
void gemm_tile(const unsigned short* __restrict__ Ahg, const unsigned short* __restrict__ Alg,
               const unsigned short* __restrict__ Bhg, const unsigned short* __restrict__ Blg,
               const float* __restrict__ bias,
               void* __restrict__ O0v, void* __restrict__ O1v,
               int M, int N, int K, long aBS, long bBS, long oBS)
{
    constexpr int CA = BM_ / 16;
    constexpr int CB = BN_ / 16;
    constexpr int AI = BM_ / 32;
    constexpr int BJ = BN_ / 32;
    static_assert(CA % 4 == 0 && CB % 4 == 0, "chunks divisible by 4 waves");

    __shared__ __align__(16) unsigned short Ash[KS][BM_*32], Bsh[KS][BN_*32];
    __shared__ __align__(16) unsigned short Asl[TERMS>=2?KS:1][TERMS>=2?BM_*32:8];
    __shared__ __align__(16) unsigned short Bsl[TERMS==3?KS:1][TERMS==3?BN_*32:8];

    const int z = blockIdx.z;
    Ahg += (size_t)z * aBS;
    Bhg += (size_t)z * bBS;
    if (TERMS >= 2) Alg += (size_t)z * aBS;
    if (TERMS == 3) Blg += (size_t)z * bBS;

    int bx = blockIdx.x, by = blockIdx.y;
    xcd_swz(bx, by);

    const int tid = threadIdx.x, lane = tid & 63, w = tid >> 6;
    const int wr = (w >> 1) * (BM_/2), wc = (w & 1) * (BN_/2);
    const int lr = lane & 15, lg = lane >> 4;
    const int m0 = by * BM_, n0 = bx * BN_;
    const int rowc = lane >> 2;
    const int colb = (lane & 3) << 4;
    const size_t rsBy = (size_t)K * 2;

    f32x4 acc[AI][BJ] = {};

    for (int k0 = 0; k0 < K; k0 += KS*32) {
#pragma unroll
        for (int s = 0; s < KS; ++s) {
#pragma unroll
            for (int c4 = 0; c4 < CA/4; ++c4) {
                const int c = c4*4 + w;
                const size_t go = (size_t)(m0 + c*16 + rowc) * rsBy + (size_t)(k0 + s*32)*2 + colb;
                gload16((const char*)Ahg + go, (char*)&Ash[s][0] + c*1024);
                if (TERMS >= 2) gload16((const char*)Alg + go, (char*)&Asl[s][0] + c*1024);
            }
#pragma unroll
            for (int c4 = 0; c4 < CB/4; ++c4) {
                const int c = c4*4 + w;
                const size_t go = (size_t)(n0 + c*16 + rowc) * rsBy + (size_t)(k0 + s*32)*2 + colb;
                gload16((const char*)Bhg + go, (char*)&Bsh[s][0] + c*1024);
                if (TERMS == 3) gload16((const char*)Blg + go, (char*)&Bsl[s][0] + c*1024);
            }
        }
        __syncthreads();

#pragma unroll
        for (int kk = 0; kk < KS; ++kk) {
            u16x8 ah[AI], bh[BJ];
#pragma unroll
            for (int i = 0; i < AI; ++i) ah[i] = *(const u16x8*)&Ash[kk][(wr + i*16 + lr)*32 + lg*8];
#pragma unroll
            for (int j = 0; j < BJ; ++j) bh[j] = *(const u16x8*)&Bsh[kk][(wc + j*16 + lr)*32 + lg*8];
            if (TERMS == 3) {
                u16x8 al[AI], bl[BJ];
#pragma unroll
                for (int i = 0; i < AI; ++i) al[i] = *(const u16x8*)&Asl[kk][(wr + i*16 + lr)*32 + lg*8];
#pragma unroll
                for (int j = 0; j < BJ; ++j) bl[j] = *(const u16x8*)&Bsl[kk][(wc + j*16 + lr)*32 + lg*8];
#pragma unroll
                for (int i = 0; i < AI; ++i)
#pragma unroll
                    for (int j = 0; j < BJ; ++j) {
                        acc[i][j] = mfma_u16<DT>(ah[i], bh[j], acc[i][j]);
                        acc[i][j] = mfma_u16<DT>(ah[i], bl[j], acc[i][j]);
                        acc[i][j] = mfma_u16<DT>(al[i], bh[j], acc[i][j]);
                    }
            } else if (TERMS == 2) {
                u16x8 al[AI];
#pragma unroll
                for (int i = 0; i < AI; ++i) al[i] = *(const u16x8*)&Asl[kk][(wr + i*16 + lr)*32 + lg*8];
#pragma unroll
                for (int i = 0; i < AI; ++i)
#pragma unroll
                    for (int j = 0; j < BJ; ++j) {
                        acc[i][j] = mfma_u16<DT>(ah[i], bh[j], acc[i][j]);
                        acc[i][j] = mfma_u16<DT>(al[i], bh[j], acc[i][j]);
                    }
            } else {
#pragma unroll
                for (int i = 0; i < AI; ++i)
#pragma unroll
                    for (int j = 0; j < BJ; ++j)
                        acc[i][j] = mfma_u16<DT>(ah[i], bh[j], acc[i][j]);
            }
        }
        __syncthreads();
    }

    if (EPI == 0) {
        float* C = (float*)O0v + (size_t)z * oBS;
#pragma unroll
        for (int j = 0; j < BJ; ++j) {
            const int col = n0 + wc + j*16 + lr;
#pragma unroll
            for (int i = 0; i < AI; ++i)
#pragma unroll
                for (int r = 0; r < 4; ++r)
                    C[(size_t)(m0 + wr + i*16 + lg*4 + r) * N + col] = acc[i][j][r];
        }
    } else {
        unsigned short* Chi = (unsigned short*)O0v + (size_t)z * oBS;
        unsigned short* Clo = (unsigned short*)O1v + (size_t)z * oBS;
#pragma unroll
        for (int j = 0; j < BJ; ++j) {
            const int col = n0 + wc + j*16 + lr;
            const float bc = (EPI == 2) ? bias[col] : 0.f;
#pragma unroll
            for (int i = 0; i < AI; ++i)
#pragma unroll
                for (int r = 0; r < 4; ++r) {
                    const size_t idx = (size_t)(m0 + wr + i*16 + lg*4 + r) * N + col;
                    const float v = acc[i][j][r] + bc;
                    const unsigned short h = cvt_rne<DT>(v);
                    Chi[idx] = h;
                    Clo[idx] = cvt_rne<DT>(v - cvt_f<DT>(h));
                }
        }
    }
}

// ---------------------------------------------------------------------------
// Dual-output K+V projection (r9-proven form).
// ---------------------------------------------------------------------------
__global__ __launch_bounds__(256, 2)
void gemm_kv(const unsigned short* __restrict__ Ahg, const unsigned short* __restrict__ Alg,
             const unsigned short* __restrict__ Wk16, const unsigned short* __restrict__ Wv16,
             const float* __restrict__ bk, const float* __restrict__ bv,
             unsigned short* __restrict__ Kh, unsigned short* __restrict__ Vt,
             int M, int N, int K)
{
    constexpr int BM_ = 128, BN_ = 128, BK_ = 32;
    __shared__ __align__(16) unsigned short Ash[BM_*BK_], Asl[BM_*BK_];
    __shared__ __align__(16) unsigned short Bks[BN_*BK_], Bvs[BN_*BK_];

    int bx = blockIdx.x, by = blockIdx.y;
    xcd_swz(bx, by);

    const int tid = threadIdx.x, lane = tid & 63, w = tid >> 6;
    const int wr = (w >> 1) * 64, wc = (w & 1) * 64;
    const int lr = lane & 15, lg = lane >> 4;
    const int m0 = by * BM_, n0 = bx * BN_;
    const int rowc = lane >> 2;
    const int colb = (lane & 3) << 4;
    const size_t rsBy = (size_t)K * 2;

    f32x4 acck[4][4] = {}, accv[4][4] = {};

    for (int k0 = 0; k0 < K; k0 += BK_) {
#pragma unroll
        for (int c4 = 0; c4 < 2; ++c4) {
            const int c = c4*4 + w;
            const size_t goA = (size_t)(m0 + c*16 + rowc) * rsBy + (size_t)k0*2 + colb;
            gload16((const char*)Ahg + goA, (char*)Ash + c*1024);
            gload16((const char*)Alg + goA, (char*)Asl + c*1024);
            const size_t goB = (size_t)(n0 + c*16 + rowc) * rsBy + (size_t)k0*2 + colb;
            gload16((const char*)Wk16 + goB, (char*)Bks + c*1024);
            gload16((const char*)Wv16 + goB, (char*)Bvs + c*1024);
        }
        __syncthreads();

        u16x8 ah[4], al[4], bf[4];
#pragma unroll
        for (int i = 0; i < 4; ++i) {
            ah[i] = *(const u16x8*)&Ash[(wr + i*16 + lr)*BK_ + lg*8];
            al[i] = *(const u16x8*)&Asl[(wr + i*16 + lr)*BK_ + lg*8];
        }
#pragma unroll
        for (int j = 0; j < 4; ++j) bf[j] = *(const u16x8*)&Bks[(wc + j*16 + lr)*BK_ + lg*8];
#pragma unroll
        for (int i = 0; i < 4; ++i)
#pragma unroll
            for (int j = 0; j < 4; ++j) {
                acck[i][j] = mfma_f16(ah[i], bf[j], acck[i][j]);
                acck[i][j] = mfma_f16(al[i], bf[j], acck[i][j]);
            }
#pragma unroll
        for (int j = 0; j < 4; ++j) bf[j] = *(const u16x8*)&Bvs[(wc + j*16 + lr)*BK_ + lg*8];
#pragma unroll
        for (int i = 0; i < 4; ++i)
#pragma unroll
            for (int j = 0; j < 4; ++j) {
                accv[i][j] = mfma_f16(ah[i], bf[j], accv[i][j]);
                accv[i][j] = mfma_f16(al[i], bf[j], accv[i][j]);
            }
        __syncthreads();
    }

#pragma unroll
    for (int j = 0; j < 4; ++j) {
        const int col = n0 + wc + j*16 + lr;
        const float bck = bk[col], bcv = bv[col];
#pragma unroll
        for (int i = 0; i < 4; ++i) {
            const int row0 = m0 + wr + i*16 + lg*4;
#pragma unroll
            for (int r = 0; r < 4; ++r)
                Kh[(size_t)(row0 + r)*N + col] = h_rne(acck[i][j][r] + bck);
            const int b = row0 >> 11, t0 = row0 & 2047;
            u16x4 pk;
#pragma unroll
            for (int r = 0; r < 4; ++r) pk[r] = h_rne(accv[i][j][r] + bcv);
            *(u16x4*)&Vt[(((size_t)b*Dd + col) << 11) + t0] = pk;
        }
    }
}

// ---------------------------------------------------------------------------
// Legacy reg-convert projection (fallback when ws too small for pre-split).
// ---------------------------------------------------------------------------
template<int TERMS, int EPI>
__global__ __launch_bounds__(256, 2)
void gemm_proj(const float* __restrict__ A, const float* __restrict__ Bm,
               const float* __restrict__ bias,
               unsigned short* __restrict__ O0, unsigned short* __restrict__ O1,
               int M, int N, int K)
{
    constexpr int BM_ = 128, BN_ = 64, BK_ = 32;
    __shared__ __align__(16) unsigned short Ash[BM_*BK_], Bsh[BN_*BK_];
    __shared__ __align__(16) unsigned short Asl[TERMS==3?BM_*BK_:8], Bsl[TERMS==3?BN_*BK_:8];

    const int tid = threadIdx.x, lane = tid & 63, w = tid >> 6;
    const int wr = (w >> 1) * 64, wc = (w & 1) * 32;
    const int lr = lane & 15, lg = lane >> 4;
    const int m0 = blockIdx.y * BM_, n0 = blockIdx.x * BN_;

    f32x4 acc[4][2] = {};

    for (int k0 = 0; k0 < K; k0 += BK_) {
        float4 av[4], bv[2];
#pragma unroll
        for (int u = 0; u < 4; ++u) {
            const int f = u*256 + tid;
            av[u] = *(const float4*)(A + (size_t)(m0 + (f >> 3))*K + k0 + ((f & 7) << 2));
        }
#pragma unroll
        for (int u = 0; u < 2; ++u) {
            const int f = u*256 + tid;
            bv[u] = *(const float4*)(Bm + (size_t)(n0 + (f >> 3))*K + k0 + ((f & 7) << 2));
        }
        __syncthreads();
#pragma unroll
        for (int u = 0; u < 4; ++u) {
            const int f = u*256 + tid;
            const int row = f >> 3, ko = (f & 7) << 2;
            float a4[4]; *(float4*)a4 = av[u];
            u16x4 ah;
            if (TERMS == 3) {
                u16x4 al;
#pragma unroll
                for (int j = 0; j < 4; ++j) { ah[j] = hi_trunc(a4[j]); al[j] = hi_trunc(a4[j] - from_hi(ah[j])); }
                *(u16x4*)&Asl[row*BK_ + ko] = al;
            } else {
#pragma unroll
                for (int j = 0; j < 4; ++j) ah[j] = hi_rne(a4[j]);
            }
            *(u16x4*)&Ash[row*BK_ + ko] = ah;
        }
#pragma unroll
        for (int u = 0; u < 2; ++u) {
            const int f = u*256 + tid;
            const int row = f >> 3, ko = (f & 7) << 2;
            float b4[4]; *(float4*)b4 = bv[u];
            u16x4 bh;
            if (TERMS == 3) {
                u16x4 bl;
#pragma unroll
                for (int j = 0; j < 4; ++j) { bh[j] = hi_trunc(b4[j]); bl[j] = hi_trunc(b4[j] - from_hi(bh[j])); }
                *(u16x4*)&Bsl[row*BK_ + ko] = bl;
            } else {
#pragma unroll
                for (int j = 0; j < 4; ++j) bh[j] = hi_rne(b4[j]);
            }
            *(u16x4*)&Bsh[row*BK_ + ko] = bh;
        }
        __syncthreads();

        bf16x8 ah[4], bh[2];
#pragma unroll
        for (int i = 0; i < 4; ++i) ah[i] = *(const bf16x8*)&Ash[(wr + i*16 + lr)*BK_ + lg*8];
#pragma unroll
        for (int j = 0; j < 2; ++j) bh[j] = *(const bf16x8*)&Bsh[(wc + j*16 + lr)*BK_ + lg*8];
        if (TERMS == 3) {
            bf16x8 al[4], bl[2];
#pragma unroll
            for (int i = 0; i < 4; ++i) al[i] = *(const bf16x8*)&Asl[(wr + i*16 + lr)*BK_ + lg*8];
#pragma unroll
            for (int j = 0; j < 2; ++j) bl[j] = *(const bf16x8*)&Bsl[(wc + j*16 + lr)*BK_ + lg*8];
#pragma unroll
            for (int i = 0; i < 4; ++i)
#pragma unroll
                for (int j = 0; j < 2; ++j) {
                    acc[i][j] = mfma_bf16(ah[i], bh[j], acc[i][j]);
                    acc[i][j] = mfma_bf16(ah[i], bl[j], acc[i][j]);
                    acc[i][j] = mfma_bf16(al[i], bh[j], acc[i][j]);
                }
        } else {
#pragma unroll
            for (int i = 0; i < 4; ++i)
#pragma unroll
                for (int j = 0; j < 2; ++j)
                    acc[i][j] = mfma_bf16(ah[i], bh[j], acc[i][j]);
        }
        __syncthreads();
    }

#pragma unroll
    for (int j = 0; j < 2; ++j) {
        const int col = n0 + wc + j*16 + lr;
        const float bc = bias[col];
#pragma unroll
        for (int i = 0; i < 4; ++i) {
            if (EPI == 0) {
#pragma unroll
                for (int r = 0; r < 4; ++r) {
                    const int row = m0 + wr + i*16 + lg*4 + r;
                    const float v = acc[i][j][r] + bc;
                    const unsigned short h = h_rne(v);
                    O0[(size_t)row*N + col] = h;
                    O1[(size_t)row*N + col] = h_rne(v - h2f(h));
                }
            } else if (EPI == 2) {
#pragma unroll
                for (int r = 0; r < 4; ++r) {
                    const int row = m0 + wr + i*16 + lg*4 + r;
                    O0[(size_t)row*N + col] = h_rne(acc[i][j][r] + bc);
                }
            } else {
                const int row0 = m0 + wr + i*16 + lg*4;
                const int b = row0 >> 11, t0 = row0 & 2047;
                u16x4 pk;
#pragma unroll
                for (int r = 0; r < 4; ++r) pk[r] = h_rne(acc[i][j][r] + bc);
                *(u16x4*)&O0[(((size_t)b*Dd + col) << 11) + t0] = pk;
            }
        }
    }
}

// ---------------------------------------------------------------------------
// Row softmax over split-fp16 logits; 16B accesses; fp16 P in place over hi.
// ---------------------------------------------------------------------------
__global__ __launch_bounds__(256)
void softmax_sp(unsigned short* __restrict__ Shi, const unsigned short* __restrict__ Slo)
{
    const int tid = threadIdx.x;
    unsigned short* ph = Shi + (size_t)blockIdx.x * SKn;
    const unsigned short* pl = Slo + (size_t)blockIdx.x * SKn;
    __shared__ float red[8];

    u16x8 h8 = *(const u16x8*)&ph[tid*8];
    u16x8 l8 = *(const u16x8*)&pl[tid*8];
    float v[8];
#pragma unroll
    for (int r = 0; r < 8; ++r) v[r] = h2f(h8[r]) + h2f(l8[r]);

    float m = v[0];
#pragma unroll
    for (int r = 1; r < 8; ++r) m = fmaxf(m, v[r]);
#pragma unroll
    for (int o2 = 32; o2 > 0; o2 >>= 1) m = fmaxf(m, __shfl_down(m, o2));
    if ((tid & 63) == 0) red[tid >> 6] = m;
    __syncthreads();
    m = fmaxf(fmaxf(red[0],red[1]), fmaxf(red[2],red[3]));

    float e[8], s = 0.f;
#pragma unroll
    for (int r = 0; r < 8; ++r) { e[r] = __expf(v[r] - m); s += e[r]; }
#pragma unroll
    for (int o2 = 32; o2 > 0; o2 >>= 1) s += __shfl_down(s, o2);
    if ((tid & 63) == 0) red[4 + (tid >> 6)] = s;
    __syncthreads();
    const float inv = 1.f / ((red[4]+red[5])+(red[6]+red[7]));

    u16x8 p8;
#pragma unroll
    for (int r = 0; r < 8; ++r) p8[r] = h_rne(e[r]*inv);
    *(u16x8*)&ph[tid*8] = p8;
}

extern "C" void kernel_launch(void* const* d_in, const int* in_sizes, int n_in,
                              void* d_out, int out_size, void* d_ws, size_t ws_size,
                              hipStream_t stream)
{
    const float* x  = (const float*)d_in[0];
    const float* c  = (const float*)d_in[1];
    const float* Wq = (const float*)d_in[2];
    const float* bq = (const float*)d_in[3];
    const float* Wk = (const float*)d_in[4];
    const float* bk = (const float*)d_in[5];
    const float* Wv = (const float*)d_in[6];
    const float* bv = (const float*)d_in[7];
    float* out = (float*)d_out;

    const size_t nQ = (size_t)Bb * SQn * Dd;          // 8.39M elems
    const size_t sE = (size_t)SQn * SKn;              // 4.19M logits per batch
    const size_t nW = (size_t)Dd * Dd;                // 1.05M elems per W
    unsigned short* Qh = (unsigned short*)d_ws;       // fp16 hi
    unsigned short* Ql = Qh + nQ;                     // fp16 lo
    unsigned short* Kh = Ql + nQ;                     // fp16 single
    unsigned short* Kl = Kh + nQ;                     // region reused for W16
    unsigned short* Vt = Kl + nQ;                     // [B][D][SK] fp16
    unsigned short* Shi = Vt + nQ;                    // fp16 logits hi / P
    unsigned short* Slo = Shi + (size_t)Bb * sE;      // fp16 logits lo

    unsigned short* Wq16 = Kl;
    unsigned short* Wk16 = Kl + nW;
    unsigned short* Wv16 = Kl + 2*nW;

    unsigned short* xh = Shi;
    unsigned short* xl = Shi + nQ;
    unsigned short* ch = Slo;
    unsigned short* cl = Slo + nQ;

    const size_t needB = (size_t)(Shi - Qh) * 2 + (size_t)Bb * sE * 2 * 2;  // 151 MB
    const bool batched = ws_size >= needB;

    const dim3 blk(256);

    if (batched) {
        prep<<<dim3(4096), blk, 0, stream>>>(x, c, Wq, Wk, Wv,
                                             xh, xl, ch, cl, Wq16, Wk16, Wv16,
                                             (int)(nQ/4), (int)(nW/4));

        // Q proj: KS=2 (W-panel L2-resident; halved barriers win — r11).
        gemm_tile<2,128,128,2,2,1><<<dim3(Dd/128, (Bb*SQn)/128), blk, 0, stream>>>(
            xh, xl, Wq16, nullptr, bq, Qh, Ql, Bb*SQn, Dd, Dd, 0, 0, 0);
        gemm_kv<<<dim3(Dd/128, (Bb*SKn)/128), blk, 0, stream>>>(
            ch, cl, Wk16, Wv16, bk, bv, Kh, Vt, Bb*SKn, Dd, Dd);

        // Scores: K_eff=2048 single-term + counted-vmcnt dbuf (32 KB LDS).
        gemm_sc<<<dim3(SKn/128, SQn/128, Bb), blk, 0, stream>>>(
            Qh, Ql, Kh, Shi, Slo, SQn, SKn, Dd,
            (long)SQn*Dd, (long)SKn*Dd, (long)sE);
        softmax_sp<<<dim3(Bb*SQn), blk, 0, stream>>>(Shi, Slo);
        // PV: KS=2 (32 KB LDS keeps occupancy; halved barriers win — r11).
        gemm_tile<1,128,128,2,0,1><<<dim3(Dd/128, SQn/128, Bb), blk, 0, stream>>>(
            Shi, nullptr, Vt, nullptr, nullptr, out, nullptr, SQn, Dd, SKn,
            (long)sE, (long)Dd*SKn, (long)SQn*Dd);
    } else {
        unsigned short* ShiF = Shi;
        unsigned short* SloF = Shi + sE;
        gemm_proj<3,0><<<dim3(Dd/64, (Bb*SQn)/128), blk, 0, stream>>>(x, Wq, bq, Qh, Ql, Bb*SQn, Dd, Dd);
        gemm_proj<3,2><<<dim3(Dd/64, (Bb*SKn)/128), blk, 0, stream>>>(c, Wk, bk, Kh, nullptr, Bb*SKn, Dd, Dd);
        gemm_proj<1,1><<<dim3(Dd/64, (Bb*SKn)/128), blk, 0, stream>>>(c, Wv, bv, Vt, nullptr, Bb*SKn, Dd, Dd);
        for (int b = 0; b < Bb; ++b) {
            const size_t qoff = (size_t)b * SQn * Dd;
            const size_t koff = (size_t)b * SKn * Dd;
            gemm_tile<2,128,64,1,1,1><<<dim3(SKn/64, SQn/128, 1), blk, 0, stream>>>(
                Qh+qoff, Ql+qoff, Kh+koff, nullptr, nullptr, ShiF, SloF, SQn, SKn, Dd, 0, 0, 0);
            softmax_sp<<<dim3(SQn), blk, 0, stream>>>(ShiF, SloF);
            gemm_tile<1,64,64,1,0,1><<<dim3(Dd/64, SQn/64, 1), blk, 0, stream>>>(
                ShiF, nullptr, Vt+(size_t)b*Dd*SKn, nullptr, nullptr, out+qoff, nullptr,
                SQn, Dd, SKn, 0, 0, 0);
        }
    }
}

// Round 14
// 273.775 us; speedup vs baseline: 1.0422x; 1.0422x over previous
//
#include <hip/hip_runtime.h>

using f32x4  = __attribute__((ext_vector_type(4))) float;
using bf16x8 = __attribute__((ext_vector_type(8))) __bf16;
using f16x8  = __attribute__((ext_vector_type(8))) _Float16;
using u16x4  = __attribute__((ext_vector_type(4))) unsigned short;
using u16x8  = __attribute__((ext_vector_type(8))) unsigned short;

constexpr int Bb = 4, SQn = 2048, SKn = 2048, Dd = 1024;

__device__ __forceinline__ unsigned fbitsu(float x){ union{float f;unsigned u;}c; c.f=x; return c.u; }
__device__ __forceinline__ float ubitsf(unsigned u){ union{unsigned u;float f;}c; c.u=u; return c.f; }
__device__ __forceinline__ unsigned short hi_trunc(float x){ return (unsigned short)(fbitsu(x)>>16); }
__device__ __forceinline__ unsigned short hi_rne(float x){ unsigned u=fbitsu(x); return (unsigned short)((u + 0x7FFFu + ((u>>16)&1u))>>16); }
__device__ __forceinline__ float from_hi(unsigned short h){ return ubitsf(((unsigned)h)<<16); }
__device__ __forceinline__ unsigned short h_rne(float x){ _Float16 h = (_Float16)x; return __builtin_bit_cast(unsigned short, h); }
__device__ __forceinline__ float h2f(unsigned short u){ return (float)__builtin_bit_cast(_Float16, u); }

template<int DT> __device__ __forceinline__ unsigned short cvt_rne(float x){ return DT ? h_rne(x) : hi_rne(x); }
template<int DT> __device__ __forceinline__ float cvt_f(unsigned short u){ return DT ? h2f(u) : from_hi(u); }

__device__ __forceinline__ f32x4 mfma_bf16(bf16x8 a, bf16x8 b, f32x4 c){
    return __builtin_amdgcn_mfma_f32_16x16x32_bf16(a, b, c, 0, 0, 0);
}
__device__ __forceinline__ f32x4 mfma_f16(u16x8 a, u16x8 b, f32x4 c){
    return __builtin_amdgcn_mfma_f32_16x16x32_f16(
        __builtin_bit_cast(f16x8, a), __builtin_bit_cast(f16x8, b), c, 0, 0, 0);
}
template<int DT>
__device__ __forceinline__ f32x4 mfma_u16(u16x8 a, u16x8 b, f32x4 c){
    if constexpr (DT) return mfma_f16(a, b, c);
    else return __builtin_amdgcn_mfma_f32_16x16x32_bf16(
        __builtin_bit_cast(bf16x8, a), __builtin_bit_cast(bf16x8, b), c, 0, 0, 0);
}

__device__ __forceinline__ void gload16(const void* g, void* l){
    __builtin_amdgcn_global_load_lds(
        (const __attribute__((address_space(1))) unsigned int*)g,
        (__attribute__((address_space(3))) unsigned int*)l, 16, 0, 0);
}

// Bijective XCD-aware block swizzle (T1). Requires nwg % 8 == 0.
__device__ __forceinline__ void xcd_swz(int& bx, int& by){
    const int nx = gridDim.x, nwg = nx * gridDim.y;
    int l = by * nx + bx;
    l = (l & 7) * (nwg >> 3) + (l >> 3);
    bx = l % nx; by = l / nx;
}

// ---------------------------------------------------------------------------
// Fused prep: x/c fp32 -> fp16 hi/lo splits, plus Wq/Wk/Wv fp32 -> fp16 RNE.
// ---------------------------------------------------------------------------
__global__ __launch_bounds__(256)
void prep(const float* __restrict__ x, const float* __restrict__ c,
          const float* __restrict__ Wq, const float* __restrict__ Wk,
          const float* __restrict__ Wv,
          unsigned short* __restrict__ xh, unsigned short* __restrict__ xl,
          unsigned short* __restrict__ ch, unsigned short* __restrict__ cl,
          unsigned short* __restrict__ oq, unsigned short* __restrict__ ok,
          unsigned short* __restrict__ ov,
          int n4, int nw4)
{
    const int total = 2*n4 + 3*nw4;
    const int stride = gridDim.x * 256;
    for (int i = blockIdx.x * 256 + threadIdx.x; i < total; i += stride) {
        if (i < 2*n4) {
            const bool second = (i >= n4);
            const int j = second ? i - n4 : i;
            const float* in = second ? c : x;
            unsigned short* hi = second ? ch : xh;
            unsigned short* lo = second ? cl : xl;
            float a[4]; *(float4*)a = *(const float4*)(in + (size_t)j * 4);
            u16x4 h, l;
#pragma unroll
            for (int r = 0; r < 4; ++r) {
                h[r] = h_rne(a[r]);
                l[r] = h_rne(a[r] - h2f(h[r]));
            }
            *(u16x4*)&hi[(size_t)j * 4] = h;
            *(u16x4*)&lo[(size_t)j * 4] = l;
        } else {
            int j = i - 2*n4;
            const float* src; unsigned short* dst;
            if (j < nw4)          { src = Wq; dst = oq; }
            else if (j < 2*nw4)   { src = Wk; dst = ok; j -= nw4; }
            else                  { src = Wv; dst = ov; j -= 2*nw4; }
            float a[4]; *(float4*)a = *(const float4*)(src + (size_t)j * 4);
            u16x4 h;
#pragma unroll
            for (int r = 0; r < 4; ++r) h[r] = h_rne(a[r]);
            *(u16x4*)&dst[(size_t)j * 4] = h;
        }
    }
}

// ---------------------------------------------------------------------------
// Unified 16-bit NT GEMM, single-buffer (r9-proven sync structure).
// K-step = KS*32, LDS as KS separate 32-col sub-arrays (64B rows always).
// KS=2 wins when B-panel is L2-resident (proj); KS=1 when staging streams
// from HBM (scores) [measured r11/r12]. K-concat single-term variant was
// tried (r13): FETCH 82->148 MB, staging-bound, REGRESSED — do not revisit.
// DT=0: bf16; DT=1: fp16. TERMS=3/2/1.
// EPI=0: fp32 out. EPI=1: split u16 out. EPI=2: split fp16 + bias (Q proj).
// ---------------------------------------------------------------------------
template<int TERMS, int BM_, int BN_, int KS, int EPI, int DT>
__global__ __launch_bounds__(256, 2)
void gemm_tile(const unsigned short* __restrict__ Ahg, const unsigned short* __restrict__ Alg,
               const unsigned short* __restrict__ Bhg, const unsigned short* __restrict__ Blg,
               const float* __restrict__ bias,
               void* __restrict__ O0v, void* __restrict__ O1v,
               int M, int N, int K, long aBS, long bBS, long oBS)
{
    constexpr int CA = BM_ / 16;
    constexpr int CB = BN_ / 16;
    constexpr int AI = BM_ / 32;
    constexpr int BJ = BN_ / 32;
    static_assert(CA % 4 == 0 && CB % 4 == 0, "chunks divisible by 4 waves");

    __shared__ __align__(16) unsigned short Ash[KS][BM_*32], Bsh[KS][BN_*32];
    __shared__ __align__(16) unsigned short Asl[TERMS>=2?KS:1][TERMS>=2?BM_*32:8];
    __shared__ __align__(16) unsigned short Bsl[TERMS==3?KS:1][TERMS==3?BN_*32:8];

    const int z = blockIdx.z;
    Ahg += (size_t)z * aBS;
    Bhg += (size_t)z * bBS;
    if (TERMS >= 2) Alg += (size_t)z * aBS;
    if (TERMS == 3) Blg += (size_t)z * bBS;

    int bx = blockIdx.x, by = blockIdx.y;
    xcd_swz(bx, by);

    const int tid = threadIdx.x, lane = tid & 63, w = tid >> 6;
    const int wr = (w >> 1) * (BM_/2), wc = (w & 1) * (BN_/2);
    const int lr = lane & 15, lg = lane >> 4;
    const int m0 = by * BM_, n0 = bx * BN_;
    const int rowc = lane >> 2;
    const int colb = (lane & 3) << 4;
    const size_t rsBy = (size_t)K * 2;

    f32x4 acc[AI][BJ] = {};

    for (int k0 = 0; k0 < K; k0 += KS*32) {
#pragma unroll
        for (int s = 0; s < KS; ++s) {
#pragma unroll
            for (int c4 = 0; c4 < CA/4; ++c4) {
                const int c = c4*4 + w;
                const size_t go = (size_t)(m0 + c*16 + rowc) * rsBy + (size_t)(k0 + s*32)*2 + colb;
                gload16((const char*)Ahg + go, (char*)&Ash[s][0] + c*1024);
                if (TERMS >= 2) gload16((const char*)Alg + go, (char*)&Asl[s][0] + c*1024);
            }
#pragma unroll
            for (int c4 = 0; c4 < CB/4; ++c4) {
                const int c = c4*4 + w;
                const size_t go = (size_t)(n0 + c*16 + rowc) * rsBy + (size_t)(k0 + s*32)*2 + colb;
                gload16((const char*)Bhg + go, (char*)&Bsh[s][0] + c*1024);
                if (TERMS == 3) gload16((const char*)Blg + go, (char*)&Bsl[s][0] + c*1024);
            }
        }
        __syncthreads();

#pragma unroll
        for (int kk = 0; kk < KS; ++kk) {
            u16x8 ah[AI], bh[BJ];
#pragma unroll
            for (int i = 0; i < AI; ++i) ah[i] = *(const u16x8*)&Ash[kk][(wr + i*16 + lr)*32 + lg*8];
#pragma unroll
            for (int j = 0; j < BJ; ++j) bh[j] = *(const u16x8*)&Bsh[kk][(wc + j*16 + lr)*32 + lg*8];
            if (TERMS == 3) {
                u16x8 al[AI], bl[BJ];
#pragma unroll
                for (int i = 0; i < AI; ++i) al[i] = *(const u16x8*)&Asl[kk][(wr + i*16 + lr)*32 + lg*8];
#pragma unroll
                for (int j = 0; j < BJ; ++j) bl[j] = *(const u16x8*)&Bsl[kk][(wc + j*16 + lr)*32 + lg*8];
#pragma unroll
                for (int i = 0; i < AI; ++i)
#pragma unroll
                    for (int j = 0; j < BJ; ++j) {
                        acc[i][j] = mfma_u16<DT>(ah[i], bh[j], acc[i][j]);
                        acc[i][j] = mfma_u16<DT>(ah[i], bl[j], acc[i][j]);
                        acc[i][j] = mfma_u16<DT>(al[i], bh[j], acc[i][j]);
                    }
            } else if (TERMS == 2) {
                u16x8 al[AI];
#pragma unroll
                for (int i = 0; i < AI; ++i) al[i] = *(const u16x8*)&Asl[kk][(wr + i*16 + lr)*32 + lg*8];
#pragma unroll
                for (int i = 0; i < AI; ++i)
#pragma unroll
                    for (int j = 0; j < BJ; ++j) {
                        acc[i][j] = mfma_u16<DT>(ah[i], bh[j], acc[i][j]);
                        acc[i][j] = mfma_u16<DT>(al[i], bh[j], acc[i][j]);
                    }
            } else {
#pragma unroll
                for (int i = 0; i < AI; ++i)
#pragma unroll
                    for (int j = 0; j < BJ; ++j)
                        acc[i][j] = mfma_u16<DT>(ah[i], bh[j], acc[i][j]);
            }
        }
        __syncthreads();
    }

    if (EPI == 0) {
        float* C = (float*)O0v + (size_t)z * oBS;
#pragma unroll
        for (int j = 0; j < BJ; ++j) {
            const int col = n0 + wc + j*16 + lr;
#pragma unroll
            for (int i = 0; i < AI; ++i)
#pragma unroll
                for (int r = 0; r < 4; ++r)
                    C[(size_t)(m0 + wr + i*16 + lg*4 + r) * N + col] = acc[i][j][r];
        }
    } else {
        unsigned short* Chi = (unsigned short*)O0v + (size_t)z * oBS;
        unsigned short* Clo = (unsigned short*)O1v + (size_t)z * oBS;
#pragma unroll
        for (int j = 0; j < BJ; ++j) {
            const int col = n0 + wc + j*16 + lr;
            const float bc = (EPI == 2) ? bias[col] : 0.f;
#pragma unroll
            for (int i = 0; i < AI; ++i)
#pragma unroll
                for (int r = 0; r < 4; ++r) {
                    const size_t idx = (size_t)(m0 + wr + i*16 + lg*4 + r) * N + col;
                    const float v = acc[i][j][r] + bc;
                    const unsigned short h = cvt_rne<DT>(v);
                    Chi[idx] = h;
                    Clo[idx] = cvt_rne<DT>(v - cvt_f<DT>(h));
                }
        }
    }
}

// ---------------------------------------------------------------------------
// Dual-output K+V projection (r9-proven form).
// ---------------------------------------------------------------------------
__global__ __launch_bounds__(256, 2)
void gemm_kv(const unsigned short* __restrict__ Ahg, const unsigned short* __restrict__ Alg,
             const unsigned short* __restrict__ Wk16, const unsigned short* __restrict__ Wv16,
             const float* __restrict__ bk, const float* __restrict__ bv,
             unsigned short* __restrict__ Kh, unsigned short* __restrict__ Vt,
             int M, int N, int K)
{
    constexpr int BM_ = 128, BN_ = 128, BK_ = 32;
    __shared__ __align__(16) unsigned short Ash[BM_*BK_], Asl[BM_*BK_];
    __shared__ __align__(16) unsigned short Bks[BN_*BK_], Bvs[BN_*BK_];

    int bx = blockIdx.x, by = blockIdx.y;
    xcd_swz(bx, by);

    const int tid = threadIdx.x, lane = tid & 63, w = tid >> 6;
    const int wr = (w >> 1) * 64, wc = (w & 1) * 64;
    const int lr = lane & 15, lg = lane >> 4;
    const int m0 = by * BM_, n0 = bx * BN_;
    const int rowc = lane >> 2;
    const int colb = (lane & 3) << 4;
    const size_t rsBy = (size_t)K * 2;

    f32x4 acck[4][4] = {}, accv[4][4] = {};

    for (int k0 = 0; k0 < K; k0 += BK_) {
#pragma unroll
        for (int c4 = 0; c4 < 2; ++c4) {
            const int c = c4*4 + w;
            const size_t goA = (size_t)(m0 + c*16 + rowc) * rsBy + (size_t)k0*2 + colb;
            gload16((const char*)Ahg + goA, (char*)Ash + c*1024);
            gload16((const char*)Alg + goA, (char*)Asl + c*1024);
            const size_t goB = (size_t)(n0 + c*16 + rowc) * rsBy + (size_t)k0*2 + colb;
            gload16((const char*)Wk16 + goB, (char*)Bks + c*1024);
            gload16((const char*)Wv16 + goB, (char*)Bvs + c*1024);
        }
        __syncthreads();

        u16x8 ah[4], al[4], bf[4];
#pragma unroll
        for (int i = 0; i < 4; ++i) {
            ah[i] = *(const u16x8*)&Ash[(wr + i*16 + lr)*BK_ + lg*8];
            al[i] = *(const u16x8*)&Asl[(wr + i*16 + lr)*BK_ + lg*8];
        }
#pragma unroll
        for (int j = 0; j < 4; ++j) bf[j] = *(const u16x8*)&Bks[(wc + j*16 + lr)*BK_ + lg*8];
#pragma unroll
        for (int i = 0; i < 4; ++i)
#pragma unroll
            for (int j = 0; j < 4; ++j) {
                acck[i][j] = mfma_f16(ah[i], bf[j], acck[i][j]);
                acck[i][j] = mfma_f16(al[i], bf[j], acck[i][j]);
            }
#pragma unroll
        for (int j = 0; j < 4; ++j) bf[j] = *(const u16x8*)&Bvs[(wc + j*16 + lr)*BK_ + lg*8];
#pragma unroll
        for (int i = 0; i < 4; ++i)
#pragma unroll
            for (int j = 0; j < 4; ++j) {
                accv[i][j] = mfma_f16(ah[i], bf[j], accv[i][j]);
                accv[i][j] = mfma_f16(al[i], bf[j], accv[i][j]);
            }
        __syncthreads();
    }

#pragma unroll
    for (int j = 0; j < 4; ++j) {
        const int col = n0 + wc + j*16 + lr;
        const float bck = bk[col], bcv = bv[col];
#pragma unroll
        for (int i = 0; i < 4; ++i) {
            const int row0 = m0 + wr + i*16 + lg*4;
#pragma unroll
            for (int r = 0; r < 4; ++r)
                Kh[(size_t)(row0 + r)*N + col] = h_rne(acck[i][j][r] + bck);
            const int b = row0 >> 11, t0 = row0 & 2047;
            u16x4 pk;
#pragma unroll
            for (int r = 0; r < 4; ++r) pk[r] = h_rne(accv[i][j][r] + bcv);
            *(u16x4*)&Vt[(((size_t)b*Dd + col) << 11) + t0] = pk;
        }
    }
}

// ---------------------------------------------------------------------------
// Legacy reg-convert projection (fallback when ws too small for pre-split).
// ---------------------------------------------------------------------------
template<int TERMS, int EPI>
__global__ __launch_bounds__(256, 2)
void gemm_proj(const float* __restrict__ A, const float* __restrict__ Bm,
               const float* __restrict__ bias,
               unsigned short* __restrict__ O0, unsigned short* __restrict__ O1,
               int M, int N, int K)
{
    constexpr int BM_ = 128, BN_ = 64, BK_ = 32;
    __shared__ __align__(16) unsigned short Ash[BM_*BK_], Bsh[BN_*BK_];
    __shared__ __align__(16) unsigned short Asl[TERMS==3?BM_*BK_:8], Bsl[TERMS==3?BN_*BK_:8];

    const int tid = threadIdx.x, lane = tid & 63, w = tid >> 6;
    const int wr = (w >> 1) * 64, wc = (w & 1) * 32;
    const int lr = lane & 15, lg = lane >> 4;
    const int m0 = blockIdx.y * BM_, n0 = blockIdx.x * BN_;

    f32x4 acc[4][2] = {};

    for (int k0 = 0; k0 < K; k0 += BK_) {
        float4 av[4], bv[2];
#pragma unroll
        for (int u = 0; u < 4; ++u) {
            const int f = u*256 + tid;
            av[u] = *(const float4*)(A + (size_t)(m0 + (f >> 3))*K + k0 + ((f & 7) << 2));
        }
#pragma unroll
        for (int u = 0; u < 2; ++u) {
            const int f = u*256 + tid;
            bv[u] = *(const float4*)(Bm + (size_t)(n0 + (f >> 3))*K + k0 + ((f & 7) << 2));
        }
        __syncthreads();
#pragma unroll
        for (int u = 0; u < 4; ++u) {
            const int f = u*256 + tid;
            const int row = f >> 3, ko = (f & 7) << 2;
            float a4[4]; *(float4*)a4 = av[u];
            u16x4 ah;
            if (TERMS == 3) {
                u16x4 al;
#pragma unroll
                for (int j = 0; j < 4; ++j) { ah[j] = hi_trunc(a4[j]); al[j] = hi_trunc(a4[j] - from_hi(ah[j])); }
                *(u16x4*)&Asl[row*BK_ + ko] = al;
            } else {
#pragma unroll
                for (int j = 0; j < 4; ++j) ah[j] = hi_rne(a4[j]);
            }
            *(u16x4*)&Ash[row*BK_ + ko] = ah;
        }
#pragma unroll
        for (int u = 0; u < 2; ++u) {
            const int f = u*256 + tid;
            const int row = f >> 3, ko = (f & 7) << 2;
            float b4[4]; *(float4*)b4 = bv[u];
            u16x4 bh;
            if (TERMS == 3) {
                u16x4 bl;
#pragma unroll
                for (int j = 0; j < 4; ++j) { bh[j] = hi_trunc(b4[j]); bl[j] = hi_trunc(b4[j] - from_hi(bh[j])); }
                *(u16x4*)&Bsl[row*BK_ + ko] = bl;
            } else {
#pragma unroll
                for (int j = 0; j < 4; ++j) bh[j] = hi_rne(b4[j]);
            }
            *(u16x4*)&Bsh[row*BK_ + ko] = bh;
        }
        __syncthreads();

        bf16x8 ah[4], bh[2];
#pragma unroll
        for (int i = 0; i < 4; ++i) ah[i] = *(const bf16x8*)&Ash[(wr + i*16 + lr)*BK_ + lg*8];
#pragma unroll
        for (int j = 0; j < 2; ++j) bh[j] = *(const bf16x8*)&Bsh[(wc + j*16 + lr)*BK_ + lg*8];
        if (TERMS == 3) {
            bf16x8 al[4], bl[2];
#pragma unroll
            for (int i = 0; i < 4; ++i) al[i] = *(const bf16x8*)&Asl[(wr + i*16 + lr)*BK_ + lg*8];
#pragma unroll
            for (int j = 0; j < 2; ++j) bl[j] = *(const bf16x8*)&Bsl[(wc + j*16 + lr)*BK_ + lg*8];
#pragma unroll
            for (int i = 0; i < 4; ++i)
#pragma unroll
                for (int j = 0; j < 2; ++j) {
                    acc[i][j] = mfma_bf16(ah[i], bh[j], acc[i][j]);
                    acc[i][j] = mfma_bf16(ah[i], bl[j], acc[i][j]);
                    acc[i][j] = mfma_bf16(al[i], bh[j], acc[i][j]);
                }
        } else {
#pragma unroll
            for (int i = 0; i < 4; ++i)
#pragma unroll
                for (int j = 0; j < 2; ++j)
                    acc[i][j] = mfma_bf16(ah[i], bh[j], acc[i][j]);
        }
        __syncthreads();
    }

#pragma unroll
    for (int j = 0; j < 2; ++j) {
        const int col = n0 + wc + j*16 + lr;
        const float bc = bias[col];
#pragma unroll
        for (int i = 0; i < 4; ++i) {
            if (EPI == 0) {
#pragma unroll
                for (int r = 0; r < 4; ++r) {
                    const int row = m0 + wr + i*16 + lg*4 + r;
                    const float v = acc[i][j][r] + bc;
                    const unsigned short h = h_rne(v);
                    O0[(size_t)row*N + col] = h;
                    O1[(size_t)row*N + col] = h_rne(v - h2f(h));
                }
            } else if (EPI == 2) {
#pragma unroll
                for (int r = 0; r < 4; ++r) {
                    const int row = m0 + wr + i*16 + lg*4 + r;
                    O0[(size_t)row*N + col] = h_rne(acc[i][j][r] + bc);
                }
            } else {
                const int row0 = m0 + wr + i*16 + lg*4;
                const int b = row0 >> 11, t0 = row0 & 2047;
                u16x4 pk;
#pragma unroll
                for (int r = 0; r < 4; ++r) pk[r] = h_rne(acc[i][j][r] + bc);
                *(u16x4*)&O0[(((size_t)b*Dd + col) << 11) + t0] = pk;
            }
        }
    }
}

// ---------------------------------------------------------------------------
// Row softmax over split-fp16 logits; 16B accesses; fp16 P in place over hi.
// ---------------------------------------------------------------------------
__global__ __launch_bounds__(256)
void softmax_sp(unsigned short* __restrict__ Shi, const unsigned short* __restrict__ Slo)
{
    const int tid = threadIdx.x;
    unsigned short* ph = Shi + (size_t)blockIdx.x * SKn;
    const unsigned short* pl = Slo + (size_t)blockIdx.x * SKn;
    __shared__ float red[8];

    u16x8 h8 = *(const u16x8*)&ph[tid*8];
    u16x8 l8 = *(const u16x8*)&pl[tid*8];
    float v[8];
#pragma unroll
    for (int r = 0; r < 8; ++r) v[r] = h2f(h8[r]) + h2f(l8[r]);

    float m = v[0];
#pragma unroll
    for (int r = 1; r < 8; ++r) m = fmaxf(m, v[r]);
#pragma unroll
    for (int o2 = 32; o2 > 0; o2 >>= 1) m = fmaxf(m, __shfl_down(m, o2));
    if ((tid & 63) == 0) red[tid >> 6] = m;
    __syncthreads();
    m = fmaxf(fmaxf(red[0],red[1]), fmaxf(red[2],red[3]));

    float e[8], s = 0.f;
#pragma unroll
    for (int r = 0; r < 8; ++r) { e[r] = __expf(v[r] - m); s += e[r]; }
#pragma unroll
    for (int o2 = 32; o2 > 0; o2 >>= 1) s += __shfl_down(s, o2);
    if ((tid & 63) == 0) red[4 + (tid >> 6)] = s;
    __syncthreads();
    const float inv = 1.f / ((red[4]+red[5])+(red[6]+red[7]));

    u16x8 p8;
#pragma unroll
    for (int r = 0; r < 8; ++r) p8[r] = h_rne(e[r]*inv);
    *(u16x8*)&ph[tid*8] = p8;
}

extern "C" void kernel_launch(void* const* d_in, const int* in_sizes, int n_in,
                              void* d_out, int out_size, void* d_ws, size_t ws_size,
                              hipStream_t stream)
{
    const float* x  = (const float*)d_in[0];
    const float* c  = (const float*)d_in[1];
    const float* Wq = (const float*)d_in[2];
    const float* bq = (const float*)d_in[3];
    const float* Wk = (const float*)d_in[4];
    const float* bk = (const float*)d_in[5];
    const float* Wv = (const float*)d_in[6];
    const float* bv = (const float*)d_in[7];
    float* out = (float*)d_out;

    const size_t nQ = (size_t)Bb * SQn * Dd;          // 8.39M elems
    const size_t sE = (size_t)SQn * SKn;              // 4.19M logits per batch
    const size_t nW = (size_t)Dd * Dd;                // 1.05M elems per W
    unsigned short* Qh = (unsigned short*)d_ws;       // fp16 hi
    unsigned short* Ql = Qh + nQ;                     // fp16 lo
    unsigned short* Kh = Ql + nQ;                     // fp16 single
    unsigned short* Kl = Kh + nQ;                     // region reused for W16
    unsigned short* Vt = Kl + nQ;                     // [B][D][SK] fp16
    unsigned short* Shi = Vt + nQ;                    // fp16 logits hi / P
    unsigned short* Slo = Shi + (size_t)Bb * sE;      // fp16 logits lo

    unsigned short* Wq16 = Kl;
    unsigned short* Wk16 = Kl + nW;
    unsigned short* Wv16 = Kl + 2*nW;

    unsigned short* xh = Shi;
    unsigned short* xl = Shi + nQ;
    unsigned short* ch = Slo;
    unsigned short* cl = Slo + nQ;

    const size_t needB = (size_t)(Shi - Qh) * 2 + (size_t)Bb * sE * 2 * 2;  // 151 MB
    const bool batched = ws_size >= needB;

    const dim3 blk(256);

    if (batched) {
        prep<<<dim3(4096), blk, 0, stream>>>(x, c, Wq, Wk, Wv,
                                             xh, xl, ch, cl, Wq16, Wk16, Wv16,
                                             (int)(nQ/4), (int)(nW/4));

        // Q proj: KS=2 (W-panel L2-resident; halved barriers win — r11).
        gemm_tile<2,128,128,2,2,1><<<dim3(Dd/128, (Bb*SQn)/128), blk, 0, stream>>>(
            xh, xl, Wq16, nullptr, bq, Qh, Ql, Bb*SQn, Dd, Dd, 0, 0, 0);
        gemm_kv<<<dim3(Dd/128, (Bb*SKn)/128), blk, 0, stream>>>(
            ch, cl, Wk16, Wv16, bk, bv, Kh, Vt, Bb*SKn, Dd, Dd);

        // Scores: KS=1, 2-term (r12-proven; K-concat variant regressed r13).
        gemm_tile<2,128,128,1,1,1><<<dim3(SKn/128, SQn/128, Bb), blk, 0, stream>>>(
            Qh, Ql, Kh, nullptr, nullptr, Shi, Slo, SQn, SKn, Dd,
            (long)SQn*Dd, (long)SKn*Dd, (long)sE);
        softmax_sp<<<dim3(Bb*SQn), blk, 0, stream>>>(Shi, Slo);
        // PV: KS=2 (32 KB LDS keeps occupancy; halved barriers win — r11).
        gemm_tile<1,128,128,2,0,1><<<dim3(Dd/128, SQn/128, Bb), blk, 0, stream>>>(
            Shi, nullptr, Vt, nullptr, nullptr, out, nullptr, SQn, Dd, SKn,
            (long)sE, (long)Dd*SKn, (long)SQn*Dd);
    } else {
        unsigned short* ShiF = Shi;
        unsigned short* SloF = Shi + sE;
        gemm_proj<3,0><<<dim3(Dd/64, (Bb*SQn)/128), blk, 0, stream>>>(x, Wq, bq, Qh, Ql, Bb*SQn, Dd, Dd);
        gemm_proj<3,2><<<dim3(Dd/64, (Bb*SKn)/128), blk, 0, stream>>>(c, Wk, bk, Kh, nullptr, Bb*SKn, Dd, Dd);
        gemm_proj<1,1><<<dim3(Dd/64, (Bb*SKn)/128), blk, 0, stream>>>(c, Wv, bv, Vt, nullptr, Bb*SKn, Dd, Dd);
        for (int b = 0; b < Bb; ++b) {
            const size_t qoff = (size_t)b * SQn * Dd;
            const size_t koff = (size_t)b * SKn * Dd;
            gemm_tile<2,128,64,1,1,1><<<dim3(SKn/64, SQn/128, 1), blk, 0, stream>>>(
                Qh+qoff, Ql+qoff, Kh+koff, nullptr, nullptr, ShiF, SloF, SQn, SKn, Dd, 0, 0, 0);
            softmax_sp<<<dim3(SQn), blk, 0, stream>>>(ShiF, SloF);
            gemm_tile<1,64,64,1,0,1><<<dim3(Dd/64, SQn/64, 1), blk, 0, stream>>>(
                ShiF, nullptr, Vt+(size_t)b*Dd*SKn, nullptr, nullptr, out+qoff, nullptr,
                SQn, Dd, SKn, 0, 0, 0);
        }
    }
}